// Round 5
// baseline (454.015 us; speedup 1.0000x reference)
//
#include <hip/hip_runtime.h>
#include <math.h>

// Problem constants: D=64 dialogues, L=64, DIM=512, G=256
// m = 3*L = 192 nodes/hyperedges per dialogue, k = 12, N = D*L = 4096
#define NDIAL 64
#define M3    192
#define DIMF  512
#define GDIM  256
#define NROW  4096
#define TOPK  12
#define INV_TAU (1.0f/0.07f)

typedef __attribute__((ext_vector_type(8))) short bf16x8;
typedef __attribute__((ext_vector_type(4))) float f32x4;
typedef _Float16 f16x8 __attribute__((ext_vector_type(8)));
typedef _Float16 f16x4v __attribute__((ext_vector_type(4)));
typedef __attribute__((address_space(3))) ushort lds_us;
typedef const __attribute__((address_space(1))) ushort gm_us;

__device__ __forceinline__ ushort f2bf(float f) {
    unsigned u = __float_as_uint(f);
    unsigned r = (u + 0x7fff + ((u >> 16) & 1)) >> 16;   // RNE
    return (ushort)r;
}

// ---------------------------------------------------------------------------
// fp32 64x64 tile GEMM helper (k1 only: top-k selection must stay fp32).
// ---------------------------------------------------------------------------
template<int KDIM>
__device__ __forceinline__ void mm64bt(
    const float* __restrict__ A, int lda,
    const float* __restrict__ B, int ldb,
    float acc[4][4])
{
    __shared__ float As[64][33];
    __shared__ float Bs[32][68];
    const int tid = threadIdx.x;
    const int tx = tid & 15, ty = tid >> 4;

#pragma unroll
    for (int r = 0; r < 4; r++)
#pragma unroll
        for (int c = 0; c < 4; c++) acc[r][c] = 0.f;

    for (int k0 = 0; k0 < KDIM; k0 += 32) {
#pragma unroll
        for (int i = 0; i < 2; i++) {
            int f = tid + i * 256;
            int m = f >> 3, k4 = f & 7;
            const float4 v4 = *(const float4*)(A + (size_t)m * lda + k0 + k4 * 4);
            As[m][k4 * 4 + 0] = v4.x;
            As[m][k4 * 4 + 1] = v4.y;
            As[m][k4 * 4 + 2] = v4.z;
            As[m][k4 * 4 + 3] = v4.w;
        }
#pragma unroll
        for (int i = 0; i < 2; i++) {
            int f = tid + i * 256;
            int n = f >> 3, k4 = f & 7;
            const float4 v4 = *(const float4*)(B + (size_t)n * ldb + k0 + k4 * 4);
            Bs[k4 * 4 + 0][n] = v4.x;
            Bs[k4 * 4 + 1][n] = v4.y;
            Bs[k4 * 4 + 2][n] = v4.z;
            Bs[k4 * 4 + 3][n] = v4.w;
        }
        __syncthreads();
#pragma unroll
        for (int kk = 0; kk < 32; kk++) {
            float4 b = *(const float4*)&Bs[kk][tx * 4];
#pragma unroll
            for (int r = 0; r < 4; r++) {
                float av = As[ty * 4 + r][kk];
                acc[r][0] += av * b.x;
                acc[r][1] += av * b.y;
                acc[r][2] += av * b.z;
                acc[r][3] += av * b.w;
            }
        }
        __syncthreads();
    }
}

// ---------------------------------------------------------------------------
// fp16 MFMA GEMM helper: block = 64 rows x (NW*64) cols, NW waves (wave w
// owns col block w). A: [M][K] row-major; B: "B^T layout" [N][K] row-major.
// C/D: row = fm*16 + qd*4 + rg, col = w*64 + fn*16 + l15.
// ---------------------------------------------------------------------------
template<int KD, int NW>
__device__ __forceinline__ void hgemm_bt(const _Float16* __restrict__ A, int lda,
                                         const _Float16* __restrict__ B, int ldb,
                                         f32x4 acc[4][4]) {
    __shared__ __align__(16) _Float16 As[64 * 40];
    __shared__ __align__(16) _Float16 Bs[NW * 64 * 40];
    const int tid = threadIdx.x;
    const int lane = tid & 63, w = tid >> 6;
    const int qd = lane >> 4, l15 = lane & 15;

#pragma unroll
    for (int fm = 0; fm < 4; fm++)
#pragma unroll
        for (int fn = 0; fn < 4; fn++)
            acc[fm][fn] = (f32x4){0.f, 0.f, 0.f, 0.f};

    for (int k0 = 0; k0 < KD; k0 += 32) {
        for (int f = tid; f < 256; f += NW * 64) {
            int row = f >> 2, c8 = f & 3;
            *(float4*)&As[row * 40 + c8 * 8] =
                *(const float4*)&A[(size_t)row * lda + k0 + c8 * 8];
        }
#pragma unroll
        for (int i = 0; i < 4; i++) {
            int f = tid + i * NW * 64;
            int row = f >> 2, c8 = f & 3;
            *(float4*)&Bs[row * 40 + c8 * 8] =
                *(const float4*)&B[(size_t)row * ldb + k0 + c8 * 8];
        }
        __syncthreads();
        f16x8 af[4], bfr[4];
#pragma unroll
        for (int fm = 0; fm < 4; fm++)
            af[fm] = *(const f16x8*)&As[(fm * 16 + l15) * 40 + qd * 8];
#pragma unroll
        for (int fn = 0; fn < 4; fn++)
            bfr[fn] = *(const f16x8*)&Bs[(w * 64 + fn * 16 + l15) * 40 + qd * 8];
#pragma unroll
        for (int fm = 0; fm < 4; fm++)
#pragma unroll
            for (int fn = 0; fn < 4; fn++)
                acc[fm][fn] = __builtin_amdgcn_mfma_f32_16x16x32_f16(
                    af[fm], bfr[fn], acc[fm][fn], 0, 0, 0);
        __syncthreads();
    }
}

__device__ __forceinline__ const float* node_ptr(const float* t, const float* a,
                                                 const float* v, int d, int j) {
    int mod = j >> 6, i = j & 63;
    const float* base = (mod == 0) ? t : (mod == 1) ? a : v;
    return base + (size_t)(d * 64 + i) * DIMF;
}

// ---- KPREP: fused fp16 conversions + per-node norms + zero-init ----
// block ranges: [0,6144) feat cvt, [6144,6272) WfcT, [6272,6336) WhT,
// [6336,9408) node norms, [9408,9456) zero rs/cs/degV/cnt, [9456,10608) zero HbT
#define F4_FEAT 1572864
__global__ void kprep(const float* __restrict__ t, const float* __restrict__ a,
                      const float* __restrict__ v, const float* __restrict__ Wfc,
                      const float* __restrict__ Wh, _Float16* __restrict__ featb,
                      _Float16* __restrict__ WfcT, _Float16* __restrict__ WhT,
                      float* __restrict__ sq, float* __restrict__ rs,
                      float* __restrict__ cs, float* __restrict__ degV,
                      unsigned* __restrict__ cnt, _Float16* __restrict__ HbT) {
    int b = blockIdx.x, tid = threadIdx.x;
    if (b < 6144) {
        int e = (b * 256 + tid) * 4;
        int d = e / (M3 * DIMF);
        int rem = e % (M3 * DIMF);
        int n = rem / DIMF, kk = rem % DIMF;
        int mod = n >> 6, i = n & 63;
        const float* src = ((mod == 0) ? t : (mod == 1) ? a : v)
                           + (size_t)(d * 64 + i) * DIMF + kk;
        float4 x = *(const float4*)src;
        f16x4v o = {(_Float16)x.x, (_Float16)x.y, (_Float16)x.z, (_Float16)x.w};
        *(f16x4v*)&featb[e] = o;
    } else if (b < 6272) {
        int e = ((b - 6144) * 256 + tid) * 4;
        int g = e >> 9, kk = e & 511;
        f16x4v o = {(_Float16)Wfc[(size_t)(kk + 0) * GDIM + g],
                    (_Float16)Wfc[(size_t)(kk + 1) * GDIM + g],
                    (_Float16)Wfc[(size_t)(kk + 2) * GDIM + g],
                    (_Float16)Wfc[(size_t)(kk + 3) * GDIM + g]};
        *(f16x4v*)&WfcT[(size_t)g * DIMF + kk] = o;
    } else if (b < 6336) {
        int e = ((b - 6272) * 256 + tid) * 4;
        int go = e >> 8, g = e & 255;
        f16x4v o = {(_Float16)Wh[(size_t)(g + 0) * GDIM + go],
                    (_Float16)Wh[(size_t)(g + 1) * GDIM + go],
                    (_Float16)Wh[(size_t)(g + 2) * GDIM + go],
                    (_Float16)Wh[(size_t)(g + 3) * GDIM + go]};
        *(f16x4v*)&WhT[(size_t)go * GDIM + g] = o;
    } else if (b < 9408) {
        int lane = tid & 63, wv = tid >> 6;
        int n = (b - 6336) * 4 + wv;
        int d = n / M3, j = n % M3;
        const float4* s4 = (const float4*)node_ptr(t, a, v, d, j);
        float s = 0.f;
#pragma unroll
        for (int q = 0; q < 2; q++) {
            float4 x = s4[lane + q * 64];
            s += x.x * x.x + x.y * x.y + x.z * x.z + x.w * x.w;
        }
        for (int o = 32; o; o >>= 1) s += __shfl_down(s, o);
        if (lane == 0) sq[n] = s;
    } else if (b < 9456) {
        int i = (b - 9408) * 256 + tid;
        rs[i] = 0.f; cs[i] = 0.f; degV[i] = 0.f;
        if (i == 0) *cnt = 0u;
    } else {
        int i = (b - 9456) * 256 + tid;   // < 294912 groups of 8 fp16
        ulonglong2 z = {0ull, 0ull};
        *(ulonglong2*)&HbT[(size_t)i * 8] = z;
    }
}

// ---- K1: clamped squared distances; symmetric -> 6 of 9 tiles ----
__global__ void k1_d2(const float* __restrict__ t, const float* __restrict__ a,
                      const float* __restrict__ v, const float* __restrict__ sq,
                      float* __restrict__ d2) {
    int tileid = blockIdx.x;             // 0..5 upper triangle
    int d = blockIdx.y;
    int bi = (tileid < 3) ? 0 : (tileid < 5) ? 1 : 2;
    int bj = (tileid < 3) ? tileid : (tileid < 5) ? tileid - 2 : 2;
    const float* A = ((bi == 0) ? t : (bi == 1) ? a : v) + (size_t)d * 64 * DIMF;
    const float* B = ((bj == 0) ? t : (bj == 1) ? a : v) + (size_t)d * 64 * DIMF;
    float acc[4][4];
    mm64bt<DIMF>(A, DIMF, B, DIMF, acc);
    int tx = threadIdx.x & 15, ty = threadIdx.x >> 4;
    const float* sqd = sq + d * M3;
    float* outp = d2 + (size_t)d * M3 * M3;
#pragma unroll
    for (int r = 0; r < 4; r++)
#pragma unroll
        for (int c = 0; c < 4; c++) {
            int il = bi * 64 + ty * 4 + r;
            int jl = bj * 64 + tx * 4 + c;
            float vv = fmaxf(sqd[il] + sqd[jl] - 2.f * acc[r][c], 0.f);
            outp[(size_t)il * M3 + jl] = vv;
            if (bi != bj) outp[(size_t)jl * M3 + il] = vv;
        }
}

// ---- K2: wave-per-row top-12 + fp16 H build + HbT scatter + degrees ----
__global__ void k2_topk(const float* __restrict__ d2, _Float16* __restrict__ Hb,
                        _Float16* __restrict__ HbT, float* __restrict__ degE,
                        float* __restrict__ degV) {
    int lane = threadIdx.x & 63, wv = threadIdx.x >> 6;
    int r = blockIdx.x * 4 + wv;                 // 0..12287
    int d = r / M3, e = r % M3;
    const float* row = d2 + (size_t)r * M3;
    float w0 = row[lane], w1 = row[lane + 64], w2 = row[lane + 128];
    bool s0 = false, s1 = false, s2 = false;
#pragma unroll
    for (int it = 0; it < TOPK; it++) {
        float bv = w0; int bi = lane;
        if (w1 < bv) { bv = w1; bi = lane + 64; }
        if (w2 < bv) { bv = w2; bi = lane + 128; }
#pragma unroll
        for (int o = 1; o < 64; o <<= 1) {
            float ov = __shfl_xor(bv, o);
            int   oi = __shfl_xor(bi, o);
            if (ov < bv || (ov == bv && oi < bi)) { bv = ov; bi = oi; }
        }
        if (bi == lane)            { s0 = true; w0 = 3.4e38f; }
        else if (bi == lane + 64)  { s1 = true; w1 = 3.4e38f; }
        else if (bi == lane + 128) { s2 = true; w2 = 3.4e38f; }
    }
    int u = e / 3;
    if (lane == u) { s0 = true; s1 = true; s2 = true; }
    float f0 = s0 ? 1.f : 0.f, f1 = s1 ? 1.f : 0.f, f2 = s2 ? 1.f : 0.f;
    _Float16* Hrow = Hb + (size_t)r * M3;
    Hrow[lane] = (_Float16)f0;
    Hrow[lane + 64] = (_Float16)f1;
    Hrow[lane + 128] = (_Float16)f2;
    float cnt = f0 + f1 + f2;
#pragma unroll
    for (int o = 1; o < 64; o <<= 1) cnt += __shfl_xor(cnt, o);
    if (lane == 0) degE[r] = cnt;
    float* dv = degV + d * M3;
    _Float16* HT = HbT + (size_t)d * M3 * M3;
    if (s0) { atomicAdd(&dv[lane], 1.f);       HT[(size_t)lane * M3 + e] = (_Float16)1.f; }
    if (s1) { atomicAdd(&dv[lane + 64], 1.f);  HT[(size_t)(lane + 64) * M3 + e] = (_Float16)1.f; }
    if (s2) { atomicAdd(&dv[lane + 128], 1.f); HT[(size_t)(lane + 128) * M3 + e] = (_Float16)1.f; }
}

// ---- K3': XT = (feat @ Wfc)^T + bfc, per dialogue. XT[d][g][n] fp16 ----
__global__ void k3_x(const _Float16* __restrict__ WfcT, const _Float16* __restrict__ featb,
                     const float* __restrict__ bfc, _Float16* __restrict__ XT) {
    int gb = blockIdx.x, d = blockIdx.y;
    const _Float16* A = WfcT + (size_t)gb * 64 * DIMF;
    const _Float16* B = featb + (size_t)d * M3 * DIMF;
    f32x4 acc[4][4];
    hgemm_bt<DIMF, 3>(A, DIMF, B, DIMF, acc);
    int lane = threadIdx.x & 63, w = threadIdx.x >> 6;
    int qd = lane >> 4, l15 = lane & 15;
    _Float16* out = XT + (size_t)d * GDIM * M3;
#pragma unroll
    for (int fm = 0; fm < 4; fm++)
#pragma unroll
        for (int rg = 0; rg < 4; rg++) {
            int g = gb * 64 + fm * 16 + qd * 4 + rg;
            float bias = bfc[g];
#pragma unroll
            for (int fn = 0; fn < 4; fn++) {
                int n = w * 64 + fn * 16 + l15;
                out[(size_t)g * M3 + n] = (_Float16)(acc[fm][fn][rg] + bias);
            }
        }
}

// ---- K4': ET = (H @ X)^T / deg_e = XT @ H(B^T).  ET[d][g][e] fp16 ----
__global__ void k4_E(const _Float16* __restrict__ XT, const _Float16* __restrict__ Hb,
                     const float* __restrict__ degE, _Float16* __restrict__ ET) {
    int gb = blockIdx.x, d = blockIdx.y;
    const _Float16* A = XT + (size_t)d * GDIM * M3 + (size_t)gb * 64 * M3;
    const _Float16* B = Hb + (size_t)d * M3 * M3;
    f32x4 acc[4][4];
    hgemm_bt<M3, 3>(A, M3, B, M3, acc);
    int lane = threadIdx.x & 63, w = threadIdx.x >> 6;
    int qd = lane >> 4, l15 = lane & 15;
    float ide[4];
#pragma unroll
    for (int fn = 0; fn < 4; fn++)
        ide[fn] = 1.f / degE[d * M3 + w * 64 + fn * 16 + l15];
    _Float16* out = ET + (size_t)d * GDIM * M3;
#pragma unroll
    for (int fm = 0; fm < 4; fm++)
#pragma unroll
        for (int rg = 0; rg < 4; rg++) {
            int g = gb * 64 + fm * 16 + qd * 4 + rg;
#pragma unroll
            for (int fn = 0; fn < 4; fn++) {
                int e = w * 64 + fn * 16 + l15;
                out[(size_t)g * M3 + e] = (_Float16)(acc[fm][fn][rg] * ide[fn]);
            }
        }
}

// ---- K5: Y = (H^T @ E) / deg_v = HbT @ ET(B^T).  Y[d][n][g] fp16 ----
__global__ void k5_Y(const _Float16* __restrict__ HbT, const _Float16* __restrict__ ET,
                     const float* __restrict__ degV, _Float16* __restrict__ Y) {
    int nb = blockIdx.x, d = blockIdx.y;
    const _Float16* A = HbT + (size_t)d * M3 * M3 + (size_t)nb * 64 * M3;
    const _Float16* B = ET + (size_t)d * GDIM * M3;
    f32x4 acc[4][4];
    hgemm_bt<M3, 4>(A, M3, B, M3, acc);
    int lane = threadIdx.x & 63, w = threadIdx.x >> 6;
    int qd = lane >> 4, l15 = lane & 15;
    _Float16* out = Y + ((size_t)d * M3 + nb * 64) * GDIM;
#pragma unroll
    for (int fm = 0; fm < 4; fm++)
#pragma unroll
        for (int rg = 0; rg < 4; rg++) {
            int ml = fm * 16 + qd * 4 + rg;
            float idv = 1.f / degV[d * M3 + nb * 64 + ml];
#pragma unroll
            for (int fn = 0; fn < 4; fn++) {
                int g = w * 64 + fn * 16 + l15;
                out[(size_t)ml * GDIM + g] = (_Float16)(acc[fm][fn][rg] * idv);
            }
        }
}

// ---- K6: out = relu(Y @ Wh + bh) -> fp32 d_out scattered [tn|an|vn] ----
__global__ void k6_out(const _Float16* __restrict__ Y, const _Float16* __restrict__ WhT,
                       const float* __restrict__ bh, float* __restrict__ outp) {
    int b = blockIdx.x;
    const _Float16* A = Y + (size_t)b * 64 * GDIM;
    f32x4 acc[4][4];
    hgemm_bt<GDIM, 4>(A, GDIM, WhT, GDIM, acc);
    int lane = threadIdx.x & 63, w = threadIdx.x >> 6;
    int qd = lane >> 4, l15 = lane & 15;
    float bb[4];
#pragma unroll
    for (int fn = 0; fn < 4; fn++)
        bb[fn] = bh[w * 64 + fn * 16 + l15];
#pragma unroll
    for (int fm = 0; fm < 4; fm++)
#pragma unroll
        for (int rg = 0; rg < 4; rg++) {
            int r = b * 64 + fm * 16 + qd * 4 + rg;
            int d = r / M3, n = r % M3;
            int mod = n >> 6, i = n & 63;
            float* orow = outp + (size_t)(d * 64 + i) * 768 + mod * GDIM;
#pragma unroll
            for (int fn = 0; fn < 4; fn++) {
                int go = w * 64 + fn * 16 + l15;
                orow[go] = fmaxf(acc[fm][fn][rg] + bb[fn], 0.f);
            }
        }
}

// ---- K7: normalize rows, write bf16 xnb[3][4096][256], CHUNK-SWIZZLED ----
// 16-B chunk c of row r is stored at slot (c&24)|((c&7)^(r&7)) so that k9's
// global_load_lds staging (verbatim slot copy, unpadded LDS) gets
// conflict-free (2-way) ds_read_b128 fragment reads.
__global__ void k7_norm(const float* __restrict__ outp, ushort* __restrict__ xnb) {
    int lane = threadIdx.x & 63, wv = threadIdx.x >> 6;
    int idx = blockIdx.x * 4 + wv;               // 0..12287
    int p = idx / NROW, r = idx % NROW;
    const float4* src = (const float4*)(outp + (size_t)r * 768 + p * GDIM);
    float4 x = src[lane];
    float s = x.x * x.x + x.y * x.y + x.z * x.z + x.w * x.w;
#pragma unroll
    for (int o = 1; o < 64; o <<= 1) s += __shfl_xor(s, o);
    float inv = 1.f / (sqrtf(s) + 1e-8f);
    ushort4 u;
    u.x = f2bf(x.x * inv);
    u.y = f2bf(x.y * inv);
    u.z = f2bf(x.z * inv);
    u.w = f2bf(x.w * inv);
    int c = lane >> 1, h = lane & 1;             // logical chunk, half
    int slot = (c & 24) | ((c & 7) ^ (r & 7));
    *(ushort4*)&xnb[((size_t)p * NROW + r) * GDIM + slot * 8 + h * 4] = u;
}

// ---- K9: bf16 MFMA sim tiles, global_load_lds staging; exp sums + diag;
//      last block folds the final loss reduction (old k10). ----
#define TILE 128
__global__ __launch_bounds__(256) void k9_mfma(const ushort* __restrict__ xnb,
                                               float* __restrict__ rs,
                                               float* __restrict__ cs,
                                               float* __restrict__ diag,
                                               unsigned* __restrict__ cnt,
                                               float* __restrict__ outp) {
    int cj = blockIdx.x, ci = blockIdx.y, p = blockIdx.z;
    int px = (p == 2) ? 1 : 0;
    int py = (p == 0) ? 1 : 2;
    const ushort* A = xnb + ((size_t)px * NROW + ci * TILE) * GDIM;
    const ushort* B = xnb + ((size_t)py * NROW + cj * TILE) * GDIM;

    __shared__ __align__(16) ushort As[TILE * 64];
    __shared__ __align__(16) ushort Bs[TILE * 64];

    const int tid = threadIdx.x;
    const int lane = tid & 63, w = tid >> 6;
    const int wrow = w >> 1, wcol = w & 1;
    const int qd = lane >> 4, l15 = lane & 15;
    const int lrow = lane >> 3, lslot = lane & 7;

    f32x4 acc[4][4] = {};

    for (int kh = 0; kh < 4; kh++) {             // BK = 64 per stage
#pragma unroll
        for (int j = 0; j < 4; j++) {
            int rr = w * 32 + j * 8 + lrow;      // per-lane global row
            __builtin_amdgcn_global_load_lds(
                (gm_us*)(A + (size_t)rr * GDIM + kh * 64 + lslot * 8),
                (lds_us*)&As[(w * 32 + j * 8) * 64], 16, 0, 0);
            __builtin_amdgcn_global_load_lds(
                (gm_us*)(B + (size_t)rr * GDIM + kh * 64 + lslot * 8),
                (lds_us*)&Bs[(w * 32 + j * 8) * 64], 16, 0, 0);
        }
        __syncthreads();
#pragma unroll
        for (int kk = 0; kk < 2; kk++) {
            bf16x8 af[4], bfv[4];
#pragma unroll
            for (int fm = 0; fm < 4; fm++) {
                int ar = wrow * 64 + fm * 16 + l15;
                af[fm] = *(const bf16x8*)&As[ar * 64 + ((kk * 4 + qd) ^ (ar & 7)) * 8];
            }
#pragma unroll
            for (int fn = 0; fn < 4; fn++) {
                int br = wcol * 64 + fn * 16 + l15;
                bfv[fn] = *(const bf16x8*)&Bs[br * 64 + ((kk * 4 + qd) ^ (br & 7)) * 8];
            }
#pragma unroll
            for (int fm = 0; fm < 4; fm++)
#pragma unroll
                for (int fn = 0; fn < 4; fn++)
                    acc[fm][fn] = __builtin_amdgcn_mfma_f32_16x16x32_bf16(
                        af[fm], bfv[fn], acc[fm][fn], 0, 0, 0);
        }
        __syncthreads();
    }

    // epilogue: exp, row/col partial sums, diagonal capture
    float rloc[4][4] = {};
    float cloc[4] = {};
#pragma unroll
    for (int fm = 0; fm < 4; fm++)
#pragma unroll
        for (int fn = 0; fn < 4; fn++)
#pragma unroll
            for (int rg = 0; rg < 4; rg++) {
                float s = acc[fm][fn][rg] * INV_TAU;
                float e = __expf(s);
                rloc[fm][rg] += e;
                cloc[fn] += e;
                if (ci == cj && wrow == wcol && fm == fn && (qd * 4 + rg) == l15)
                    diag[p * NROW + ci * TILE + wrow * 64 + fm * 16 + qd * 4 + rg] = s;
            }
#pragma unroll
    for (int fm = 0; fm < 4; fm++)
#pragma unroll
        for (int rg = 0; rg < 4; rg++) {
            float s = rloc[fm][rg];
            s += __shfl_xor(s, 1);
            s += __shfl_xor(s, 2);
            s += __shfl_xor(s, 4);
            s += __shfl_xor(s, 8);
            if (l15 == 0)
                atomicAdd(&rs[p * NROW + ci * TILE + wrow * 64 + fm * 16 + qd * 4 + rg], s);
        }
#pragma unroll
    for (int fn = 0; fn < 4; fn++) {
        float s = cloc[fn];
        s += __shfl_xor(s, 16);
        s += __shfl_xor(s, 32);
        if (qd == 0)
            atomicAdd(&cs[p * NROW + cj * TILE + wcol * 64 + fn * 16 + l15], s);
    }

    // last-block loss reduction (device-scope fence + counter)
    __threadfence();
    __shared__ unsigned rank;
    if (tid == 0) rank = atomicAdd(cnt, 1u);
    __syncthreads();
    if (rank == 32 * 32 * 3 - 1) {
        __threadfence();
        float accl = 0.f;
        for (int i = tid; i < 3 * NROW; i += 256)
            accl += 2.f * diag[i] - logf(rs[i]) - logf(cs[i]);
        for (int o = 32; o; o >>= 1) accl += __shfl_down(accl, o);
        __shared__ float red[4];
        if ((tid & 63) == 0) red[tid >> 6] = accl;
        __syncthreads();
        if (tid == 0)
            outp[(size_t)NROW * 768] = -(red[0] + red[1] + red[2] + red[3]) / (NROW * 6.0f);
    }
}

extern "C" void kernel_launch(void* const* d_in, const int* in_sizes, int n_in,
                              void* d_out, int out_size, void* d_ws, size_t ws_size,
                              hipStream_t stream) {
    const float* t   = (const float*)d_in[0];
    const float* a   = (const float*)d_in[1];
    const float* v   = (const float*)d_in[2];
    const float* Wfc = (const float*)d_in[3];
    const float* bfc = (const float*)d_in[4];
    const float* Wh  = (const float*)d_in[5];
    const float* bh  = (const float*)d_in[6];
    float* outp = (float*)d_out;
    float* ws = (float*)d_ws;

    // workspace layout (floats); all offsets 16B-aligned
    float* sq    = ws;                       // 12288
    float* d2    = sq + 12288;               // 2359296 (dead after k2 -> xnb)
    float* HbF   = d2 + 2359296;             // 1179648 (fp16 Hb 12288x192)
    float* HbTF  = HbF + 1179648;            // 1179648
    float* degE  = HbTF + 1179648;           // 12288
    float* degV  = degE + 12288;             // 12288
    float* featF = degV + 12288;             // 3145728 (fp16 featb 64x192x512)
    float* WfcTF = featF + 3145728;          // 65536   (fp16 256x512)
    float* WhTF  = WfcTF + 65536;            // 32768   (fp16 256x256)
    float* XTF   = WhTF + 32768;             // 1572864 (fp16 64x256x192)
    float* ETF   = XTF + 1572864;            // 1572864
    float* YF    = ETF + 1572864;            // 1572864 (fp16 12288x256)
    float* rs    = YF + 1572864;             // 12288
    float* cs    = rs + 12288;               // 12288
    float* diag  = cs + 12288;               // 12288
    unsigned* cnt = (unsigned*)(diag + 12288);

    _Float16* Hb    = (_Float16*)HbF;
    _Float16* HbT   = (_Float16*)HbTF;
    _Float16* featb = (_Float16*)featF;
    _Float16* WfcT  = (_Float16*)WfcTF;
    _Float16* WhT   = (_Float16*)WhTF;
    _Float16* XT    = (_Float16*)XTF;
    _Float16* ET    = (_Float16*)ETF;
    _Float16* Y     = (_Float16*)YF;
    ushort*   xnb   = (ushort*)d2;           // bf16[3][4096][256] (swizzled)

    kprep  <<<10608, 256, 0, stream>>>(t, a, v, Wfc, Wh, featb, WfcT, WhT,
                                       sq, rs, cs, degV, cnt, HbT);
    k1_d2  <<<dim3(6, 64), 256, 0, stream>>>(t, a, v, sq, d2);
    k2_topk<<<3072, 256, 0, stream>>>(d2, Hb, HbT, degE, degV);
    k3_x   <<<dim3(4, 64), 192, 0, stream>>>(WfcT, featb, bfc, XT);
    k4_E   <<<dim3(4, 64), 192, 0, stream>>>(XT, Hb, degE, ET);
    k5_Y   <<<dim3(3, 64), 256, 0, stream>>>(HbT, ET, degV, Y);
    k6_out <<<192, 256, 0, stream>>>(Y, WhT, bh, outp);
    k7_norm<<<3072, 256, 0, stream>>>(outp, xnb);
    k9_mfma<<<dim3(32, 32, 3), 256, 0, stream>>>(xnb, rs, cs, diag, cnt, outp);
}

// Round 6
// 291.669 us; speedup vs baseline: 1.5566x; 1.5566x over previous
//
#include <hip/hip_runtime.h>
#include <math.h>

// Problem constants: D=64 dialogues, L=64, DIM=512, G=256
// m = 3*L = 192 nodes/hyperedges per dialogue, k = 12, N = D*L = 4096
#define NDIAL 64
#define M3    192
#define DIMF  512
#define GDIM  256
#define NROW  4096
#define TOPK  12
#define INV_TAU (1.0f/0.07f)

typedef __attribute__((ext_vector_type(8))) short bf16x8;
typedef __attribute__((ext_vector_type(4))) float f32x4;
typedef _Float16 f16x8 __attribute__((ext_vector_type(8)));
typedef _Float16 f16x4v __attribute__((ext_vector_type(4)));
typedef __attribute__((address_space(3))) ushort lds_us;
typedef const __attribute__((address_space(1))) ushort gm_us;

__device__ __forceinline__ ushort f2bf(float f) {
    unsigned u = __float_as_uint(f);
    unsigned r = (u + 0x7fff + ((u >> 16) & 1)) >> 16;   // RNE
    return (ushort)r;
}

// ---------------------------------------------------------------------------
// fp32 64x64 tile GEMM helper (k1 only: top-k selection must stay fp32).
// ---------------------------------------------------------------------------
template<int KDIM>
__device__ __forceinline__ void mm64bt(
    const float* __restrict__ A, int lda,
    const float* __restrict__ B, int ldb,
    float acc[4][4])
{
    __shared__ float As[64][33];
    __shared__ float Bs[32][68];
    const int tid = threadIdx.x;
    const int tx = tid & 15, ty = tid >> 4;

#pragma unroll
    for (int r = 0; r < 4; r++)
#pragma unroll
        for (int c = 0; c < 4; c++) acc[r][c] = 0.f;

    for (int k0 = 0; k0 < KDIM; k0 += 32) {
#pragma unroll
        for (int i = 0; i < 2; i++) {
            int f = tid + i * 256;
            int m = f >> 3, k4 = f & 7;
            const float4 v4 = *(const float4*)(A + (size_t)m * lda + k0 + k4 * 4);
            As[m][k4 * 4 + 0] = v4.x;
            As[m][k4 * 4 + 1] = v4.y;
            As[m][k4 * 4 + 2] = v4.z;
            As[m][k4 * 4 + 3] = v4.w;
        }
#pragma unroll
        for (int i = 0; i < 2; i++) {
            int f = tid + i * 256;
            int n = f >> 3, k4 = f & 7;
            const float4 v4 = *(const float4*)(B + (size_t)n * ldb + k0 + k4 * 4);
            Bs[k4 * 4 + 0][n] = v4.x;
            Bs[k4 * 4 + 1][n] = v4.y;
            Bs[k4 * 4 + 2][n] = v4.z;
            Bs[k4 * 4 + 3][n] = v4.w;
        }
        __syncthreads();
#pragma unroll
        for (int kk = 0; kk < 32; kk++) {
            float4 b = *(const float4*)&Bs[kk][tx * 4];
#pragma unroll
            for (int r = 0; r < 4; r++) {
                float av = As[ty * 4 + r][kk];
                acc[r][0] += av * b.x;
                acc[r][1] += av * b.y;
                acc[r][2] += av * b.z;
                acc[r][3] += av * b.w;
            }
        }
        __syncthreads();
    }
}

// ---------------------------------------------------------------------------
// fp16 MFMA GEMM helper: block = 64 rows x (NW*64) cols, NW waves (wave w
// owns col block w). A: [M][K] row-major; B: "B^T layout" [N][K] row-major.
// C/D: row = fm*16 + qd*4 + rg, col = w*64 + fn*16 + l15.
// ---------------------------------------------------------------------------
template<int KD, int NW>
__device__ __forceinline__ void hgemm_bt(const _Float16* __restrict__ A, int lda,
                                         const _Float16* __restrict__ B, int ldb,
                                         f32x4 acc[4][4]) {
    __shared__ __align__(16) _Float16 As[64 * 40];
    __shared__ __align__(16) _Float16 Bs[NW * 64 * 40];
    const int tid = threadIdx.x;
    const int lane = tid & 63, w = tid >> 6;
    const int qd = lane >> 4, l15 = lane & 15;

#pragma unroll
    for (int fm = 0; fm < 4; fm++)
#pragma unroll
        for (int fn = 0; fn < 4; fn++)
            acc[fm][fn] = (f32x4){0.f, 0.f, 0.f, 0.f};

    for (int k0 = 0; k0 < KD; k0 += 32) {
        for (int f = tid; f < 256; f += NW * 64) {
            int row = f >> 2, c8 = f & 3;
            *(float4*)&As[row * 40 + c8 * 8] =
                *(const float4*)&A[(size_t)row * lda + k0 + c8 * 8];
        }
#pragma unroll
        for (int i = 0; i < 4; i++) {
            int f = tid + i * NW * 64;
            int row = f >> 2, c8 = f & 3;
            *(float4*)&Bs[row * 40 + c8 * 8] =
                *(const float4*)&B[(size_t)row * ldb + k0 + c8 * 8];
        }
        __syncthreads();
        f16x8 af[4], bfr[4];
#pragma unroll
        for (int fm = 0; fm < 4; fm++)
            af[fm] = *(const f16x8*)&As[(fm * 16 + l15) * 40 + qd * 8];
#pragma unroll
        for (int fn = 0; fn < 4; fn++)
            bfr[fn] = *(const f16x8*)&Bs[(w * 64 + fn * 16 + l15) * 40 + qd * 8];
#pragma unroll
        for (int fm = 0; fm < 4; fm++)
#pragma unroll
            for (int fn = 0; fn < 4; fn++)
                acc[fm][fn] = __builtin_amdgcn_mfma_f32_16x16x32_f16(
                    af[fm], bfr[fn], acc[fm][fn], 0, 0, 0);
        __syncthreads();
    }
}

__device__ __forceinline__ const float* node_ptr(const float* t, const float* a,
                                                 const float* v, int d, int j) {
    int mod = j >> 6, i = j & 63;
    const float* base = (mod == 0) ? t : (mod == 1) ? a : v;
    return base + (size_t)(d * 64 + i) * DIMF;
}

// ---- KPREP: fused fp16 conversions + per-node norms + zero-init ----
// block ranges: [0,6144) feat cvt, [6144,6272) WfcT, [6272,6336) WhT,
// [6336,9408) node norms, [9408,9456) zero rs/cs/degV, [9456,10608) zero HbT
__global__ void kprep(const float* __restrict__ t, const float* __restrict__ a,
                      const float* __restrict__ v, const float* __restrict__ Wfc,
                      const float* __restrict__ Wh, _Float16* __restrict__ featb,
                      _Float16* __restrict__ WfcT, _Float16* __restrict__ WhT,
                      float* __restrict__ sq, float* __restrict__ rs,
                      float* __restrict__ cs, float* __restrict__ degV,
                      _Float16* __restrict__ HbT) {
    int b = blockIdx.x, tid = threadIdx.x;
    if (b < 6144) {
        int e = (b * 256 + tid) * 4;
        int d = e / (M3 * DIMF);
        int rem = e % (M3 * DIMF);
        int n = rem / DIMF, kk = rem % DIMF;
        int mod = n >> 6, i = n & 63;
        const float* src = ((mod == 0) ? t : (mod == 1) ? a : v)
                           + (size_t)(d * 64 + i) * DIMF + kk;
        float4 x = *(const float4*)src;
        f16x4v o = {(_Float16)x.x, (_Float16)x.y, (_Float16)x.z, (_Float16)x.w};
        *(f16x4v*)&featb[e] = o;
    } else if (b < 6272) {
        int e = ((b - 6144) * 256 + tid) * 4;
        int g = e >> 9, kk = e & 511;
        f16x4v o = {(_Float16)Wfc[(size_t)(kk + 0) * GDIM + g],
                    (_Float16)Wfc[(size_t)(kk + 1) * GDIM + g],
                    (_Float16)Wfc[(size_t)(kk + 2) * GDIM + g],
                    (_Float16)Wfc[(size_t)(kk + 3) * GDIM + g]};
        *(f16x4v*)&WfcT[(size_t)g * DIMF + kk] = o;
    } else if (b < 6336) {
        int e = ((b - 6272) * 256 + tid) * 4;
        int go = e >> 8, g = e & 255;
        f16x4v o = {(_Float16)Wh[(size_t)(g + 0) * GDIM + go],
                    (_Float16)Wh[(size_t)(g + 1) * GDIM + go],
                    (_Float16)Wh[(size_t)(g + 2) * GDIM + go],
                    (_Float16)Wh[(size_t)(g + 3) * GDIM + go]};
        *(f16x4v*)&WhT[(size_t)go * GDIM + g] = o;
    } else if (b < 9408) {
        int lane = tid & 63, wv = tid >> 6;
        int n = (b - 6336) * 4 + wv;
        int d = n / M3, j = n % M3;
        const float4* s4 = (const float4*)node_ptr(t, a, v, d, j);
        float s = 0.f;
#pragma unroll
        for (int q = 0; q < 2; q++) {
            float4 x = s4[lane + q * 64];
            s += x.x * x.x + x.y * x.y + x.z * x.z + x.w * x.w;
        }
        for (int o = 32; o; o >>= 1) s += __shfl_down(s, o);
        if (lane == 0) sq[n] = s;
    } else if (b < 9456) {
        int i = (b - 9408) * 256 + tid;
        rs[i] = 0.f; cs[i] = 0.f; degV[i] = 0.f;
    } else {
        int i = (b - 9456) * 256 + tid;   // < 294912 groups of 8 fp16
        ulonglong2 z = {0ull, 0ull};
        *(ulonglong2*)&HbT[(size_t)i * 8] = z;
    }
}

// ---- K1: clamped squared distances; symmetric -> 6 of 9 tiles ----
__global__ void k1_d2(const float* __restrict__ t, const float* __restrict__ a,
                      const float* __restrict__ v, const float* __restrict__ sq,
                      float* __restrict__ d2) {
    int tileid = blockIdx.x;             // 0..5 upper triangle
    int d = blockIdx.y;
    int bi = (tileid < 3) ? 0 : (tileid < 5) ? 1 : 2;
    int bj = (tileid < 3) ? tileid : (tileid < 5) ? tileid - 2 : 2;
    const float* A = ((bi == 0) ? t : (bi == 1) ? a : v) + (size_t)d * 64 * DIMF;
    const float* B = ((bj == 0) ? t : (bj == 1) ? a : v) + (size_t)d * 64 * DIMF;
    float acc[4][4];
    mm64bt<DIMF>(A, DIMF, B, DIMF, acc);
    int tx = threadIdx.x & 15, ty = threadIdx.x >> 4;
    const float* sqd = sq + d * M3;
    float* outp = d2 + (size_t)d * M3 * M3;
#pragma unroll
    for (int r = 0; r < 4; r++)
#pragma unroll
        for (int c = 0; c < 4; c++) {
            int il = bi * 64 + ty * 4 + r;
            int jl = bj * 64 + tx * 4 + c;
            float vv = fmaxf(sqd[il] + sqd[jl] - 2.f * acc[r][c], 0.f);
            outp[(size_t)il * M3 + jl] = vv;
            if (bi != bj) outp[(size_t)jl * M3 + il] = vv;
        }
}

// ---- K2: wave-per-row top-12 + fp16 H build + HbT scatter + degrees ----
__global__ void k2_topk(const float* __restrict__ d2, _Float16* __restrict__ Hb,
                        _Float16* __restrict__ HbT, float* __restrict__ degE,
                        float* __restrict__ degV) {
    int lane = threadIdx.x & 63, wv = threadIdx.x >> 6;
    int r = blockIdx.x * 4 + wv;                 // 0..12287
    int d = r / M3, e = r % M3;
    const float* row = d2 + (size_t)r * M3;
    float w0 = row[lane], w1 = row[lane + 64], w2 = row[lane + 128];
    bool s0 = false, s1 = false, s2 = false;
#pragma unroll
    for (int it = 0; it < TOPK; it++) {
        float bv = w0; int bi = lane;
        if (w1 < bv) { bv = w1; bi = lane + 64; }
        if (w2 < bv) { bv = w2; bi = lane + 128; }
#pragma unroll
        for (int o = 1; o < 64; o <<= 1) {
            float ov = __shfl_xor(bv, o);
            int   oi = __shfl_xor(bi, o);
            if (ov < bv || (ov == bv && oi < bi)) { bv = ov; bi = oi; }
        }
        if (bi == lane)            { s0 = true; w0 = 3.4e38f; }
        else if (bi == lane + 64)  { s1 = true; w1 = 3.4e38f; }
        else if (bi == lane + 128) { s2 = true; w2 = 3.4e38f; }
    }
    int u = e / 3;
    if (lane == u) { s0 = true; s1 = true; s2 = true; }
    float f0 = s0 ? 1.f : 0.f, f1 = s1 ? 1.f : 0.f, f2 = s2 ? 1.f : 0.f;
    _Float16* Hrow = Hb + (size_t)r * M3;
    Hrow[lane] = (_Float16)f0;
    Hrow[lane + 64] = (_Float16)f1;
    Hrow[lane + 128] = (_Float16)f2;
    float cnt = f0 + f1 + f2;
#pragma unroll
    for (int o = 1; o < 64; o <<= 1) cnt += __shfl_xor(cnt, o);
    if (lane == 0) degE[r] = cnt;
    float* dv = degV + d * M3;
    _Float16* HT = HbT + (size_t)d * M3 * M3;
    if (s0) { atomicAdd(&dv[lane], 1.f);       HT[(size_t)lane * M3 + e] = (_Float16)1.f; }
    if (s1) { atomicAdd(&dv[lane + 64], 1.f);  HT[(size_t)(lane + 64) * M3 + e] = (_Float16)1.f; }
    if (s2) { atomicAdd(&dv[lane + 128], 1.f); HT[(size_t)(lane + 128) * M3 + e] = (_Float16)1.f; }
}

// ---- K3': XT = (feat @ Wfc)^T + bfc, per dialogue. XT[d][g][n] fp16 ----
__global__ void k3_x(const _Float16* __restrict__ WfcT, const _Float16* __restrict__ featb,
                     const float* __restrict__ bfc, _Float16* __restrict__ XT) {
    int gb = blockIdx.x, d = blockIdx.y;
    const _Float16* A = WfcT + (size_t)gb * 64 * DIMF;
    const _Float16* B = featb + (size_t)d * M3 * DIMF;
    f32x4 acc[4][4];
    hgemm_bt<DIMF, 3>(A, DIMF, B, DIMF, acc);
    int lane = threadIdx.x & 63, w = threadIdx.x >> 6;
    int qd = lane >> 4, l15 = lane & 15;
    _Float16* out = XT + (size_t)d * GDIM * M3;
#pragma unroll
    for (int fm = 0; fm < 4; fm++)
#pragma unroll
        for (int rg = 0; rg < 4; rg++) {
            int g = gb * 64 + fm * 16 + qd * 4 + rg;
            float bias = bfc[g];
#pragma unroll
            for (int fn = 0; fn < 4; fn++) {
                int n = w * 64 + fn * 16 + l15;
                out[(size_t)g * M3 + n] = (_Float16)(acc[fm][fn][rg] + bias);
            }
        }
}

// ---- K4': ET = (H @ X)^T / deg_e = XT @ H(B^T).  ET[d][g][e] fp16 ----
__global__ void k4_E(const _Float16* __restrict__ XT, const _Float16* __restrict__ Hb,
                     const float* __restrict__ degE, _Float16* __restrict__ ET) {
    int gb = blockIdx.x, d = blockIdx.y;
    const _Float16* A = XT + (size_t)d * GDIM * M3 + (size_t)gb * 64 * M3;
    const _Float16* B = Hb + (size_t)d * M3 * M3;
    f32x4 acc[4][4];
    hgemm_bt<M3, 3>(A, M3, B, M3, acc);
    int lane = threadIdx.x & 63, w = threadIdx.x >> 6;
    int qd = lane >> 4, l15 = lane & 15;
    float ide[4];
#pragma unroll
    for (int fn = 0; fn < 4; fn++)
        ide[fn] = 1.f / degE[d * M3 + w * 64 + fn * 16 + l15];
    _Float16* out = ET + (size_t)d * GDIM * M3;
#pragma unroll
    for (int fm = 0; fm < 4; fm++)
#pragma unroll
        for (int rg = 0; rg < 4; rg++) {
            int g = gb * 64 + fm * 16 + qd * 4 + rg;
#pragma unroll
            for (int fn = 0; fn < 4; fn++) {
                int e = w * 64 + fn * 16 + l15;
                out[(size_t)g * M3 + e] = (_Float16)(acc[fm][fn][rg] * ide[fn]);
            }
        }
}

// ---- K5: Y = (H^T @ E) / deg_v = HbT @ ET(B^T).  Y[d][n][g] fp16 ----
__global__ void k5_Y(const _Float16* __restrict__ HbT, const _Float16* __restrict__ ET,
                     const float* __restrict__ degV, _Float16* __restrict__ Y) {
    int nb = blockIdx.x, d = blockIdx.y;
    const _Float16* A = HbT + (size_t)d * M3 * M3 + (size_t)nb * 64 * M3;
    const _Float16* B = ET + (size_t)d * GDIM * M3;
    f32x4 acc[4][4];
    hgemm_bt<M3, 4>(A, M3, B, M3, acc);
    int lane = threadIdx.x & 63, w = threadIdx.x >> 6;
    int qd = lane >> 4, l15 = lane & 15;
    _Float16* out = Y + ((size_t)d * M3 + nb * 64) * GDIM;
#pragma unroll
    for (int fm = 0; fm < 4; fm++)
#pragma unroll
        for (int rg = 0; rg < 4; rg++) {
            int ml = fm * 16 + qd * 4 + rg;
            float idv = 1.f / degV[d * M3 + nb * 64 + ml];
#pragma unroll
            for (int fn = 0; fn < 4; fn++) {
                int g = w * 64 + fn * 16 + l15;
                out[(size_t)ml * GDIM + g] = (_Float16)(acc[fm][fn][rg] * idv);
            }
        }
}

// ---- K6: out = relu(Y @ Wh + bh) -> fp32 d_out scattered [tn|an|vn] ----
__global__ void k6_out(const _Float16* __restrict__ Y, const _Float16* __restrict__ WhT,
                       const float* __restrict__ bh, float* __restrict__ outp) {
    int b = blockIdx.x;
    const _Float16* A = Y + (size_t)b * 64 * GDIM;
    f32x4 acc[4][4];
    hgemm_bt<GDIM, 4>(A, GDIM, WhT, GDIM, acc);
    int lane = threadIdx.x & 63, w = threadIdx.x >> 6;
    int qd = lane >> 4, l15 = lane & 15;
    float bb[4];
#pragma unroll
    for (int fn = 0; fn < 4; fn++)
        bb[fn] = bh[w * 64 + fn * 16 + l15];
#pragma unroll
    for (int fm = 0; fm < 4; fm++)
#pragma unroll
        for (int rg = 0; rg < 4; rg++) {
            int r = b * 64 + fm * 16 + qd * 4 + rg;
            int d = r / M3, n = r % M3;
            int mod = n >> 6, i = n & 63;
            float* orow = outp + (size_t)(d * 64 + i) * 768 + mod * GDIM;
#pragma unroll
            for (int fn = 0; fn < 4; fn++) {
                int go = w * 64 + fn * 16 + l15;
                orow[go] = fmaxf(acc[fm][fn][rg] + bb[fn], 0.f);
            }
        }
}

// ---- K7: normalize rows, write bf16 xnb[3][4096][256], CHUNK-SWIZZLED ----
// 16-B chunk c of row r is stored at slot (c&24)|((c&7)^(r&7)) so that k9's
// global_load_lds staging (verbatim slot copy, unpadded LDS) gets
// conflict-free (2-way) ds_read_b128 fragment reads.
__global__ void k7_norm(const float* __restrict__ outp, ushort* __restrict__ xnb) {
    int lane = threadIdx.x & 63, wv = threadIdx.x >> 6;
    int idx = blockIdx.x * 4 + wv;               // 0..12287
    int p = idx / NROW, r = idx % NROW;
    const float4* src = (const float4*)(outp + (size_t)r * 768 + p * GDIM);
    float4 x = src[lane];
    float s = x.x * x.x + x.y * x.y + x.z * x.z + x.w * x.w;
#pragma unroll
    for (int o = 1; o < 64; o <<= 1) s += __shfl_xor(s, o);
    float inv = 1.f / (sqrtf(s) + 1e-8f);
    ushort4 u;
    u.x = f2bf(x.x * inv);
    u.y = f2bf(x.y * inv);
    u.z = f2bf(x.z * inv);
    u.w = f2bf(x.w * inv);
    int c = lane >> 1, h = lane & 1;             // logical chunk, half
    int slot = (c & 24) | ((c & 7) ^ (r & 7));
    *(ushort4*)&xnb[((size_t)p * NROW + r) * GDIM + slot * 8 + h * 4] = u;
}

// ---- K9: bf16 MFMA sim tiles, global_load_lds staging; exp sums + diag ----
// NO device fences here (R5's per-block __threadfence invalidated shared L2
// copies of xnb -> reads fell to L3 -> 3x slowdown). Loss reduced in k10.
#define TILE 128
__global__ __launch_bounds__(256) void k9_mfma(const ushort* __restrict__ xnb,
                                               float* __restrict__ rs,
                                               float* __restrict__ cs,
                                               float* __restrict__ diag) {
    int cj = blockIdx.x, ci = blockIdx.y, p = blockIdx.z;
    int px = (p == 2) ? 1 : 0;
    int py = (p == 0) ? 1 : 2;
    const ushort* A = xnb + ((size_t)px * NROW + ci * TILE) * GDIM;
    const ushort* B = xnb + ((size_t)py * NROW + cj * TILE) * GDIM;

    __shared__ __align__(16) ushort As[TILE * 64];
    __shared__ __align__(16) ushort Bs[TILE * 64];

    const int tid = threadIdx.x;
    const int lane = tid & 63, w = tid >> 6;
    const int wrow = w >> 1, wcol = w & 1;
    const int qd = lane >> 4, l15 = lane & 15;
    const int lrow = lane >> 3, lslot = lane & 7;

    f32x4 acc[4][4] = {};

    for (int kh = 0; kh < 4; kh++) {             // BK = 64 per stage
#pragma unroll
        for (int j = 0; j < 4; j++) {
            int rr = w * 32 + j * 8 + lrow;      // per-lane global row
            __builtin_amdgcn_global_load_lds(
                (gm_us*)(A + (size_t)rr * GDIM + kh * 64 + lslot * 8),
                (lds_us*)&As[(w * 32 + j * 8) * 64], 16, 0, 0);
            __builtin_amdgcn_global_load_lds(
                (gm_us*)(B + (size_t)rr * GDIM + kh * 64 + lslot * 8),
                (lds_us*)&Bs[(w * 32 + j * 8) * 64], 16, 0, 0);
        }
        __syncthreads();
#pragma unroll
        for (int kk = 0; kk < 2; kk++) {
            bf16x8 af[4], bfv[4];
#pragma unroll
            for (int fm = 0; fm < 4; fm++) {
                int ar = wrow * 64 + fm * 16 + l15;
                af[fm] = *(const bf16x8*)&As[ar * 64 + ((kk * 4 + qd) ^ (ar & 7)) * 8];
            }
#pragma unroll
            for (int fn = 0; fn < 4; fn++) {
                int br = wcol * 64 + fn * 16 + l15;
                bfv[fn] = *(const bf16x8*)&Bs[br * 64 + ((kk * 4 + qd) ^ (br & 7)) * 8];
            }
#pragma unroll
            for (int fm = 0; fm < 4; fm++)
#pragma unroll
                for (int fn = 0; fn < 4; fn++)
                    acc[fm][fn] = __builtin_amdgcn_mfma_f32_16x16x32_bf16(
                        af[fm], bfv[fn], acc[fm][fn], 0, 0, 0);
        }
        __syncthreads();
    }

    // epilogue: exp, row/col partial sums, diagonal capture
    float rloc[4][4] = {};
    float cloc[4] = {};
#pragma unroll
    for (int fm = 0; fm < 4; fm++)
#pragma unroll
        for (int fn = 0; fn < 4; fn++)
#pragma unroll
            for (int rg = 0; rg < 4; rg++) {
                float s = acc[fm][fn][rg] * INV_TAU;
                float e = __expf(s);
                rloc[fm][rg] += e;
                cloc[fn] += e;
                if (ci == cj && wrow == wcol && fm == fn && (qd * 4 + rg) == l15)
                    diag[p * NROW + ci * TILE + wrow * 64 + fm * 16 + qd * 4 + rg] = s;
            }
#pragma unroll
    for (int fm = 0; fm < 4; fm++)
#pragma unroll
        for (int rg = 0; rg < 4; rg++) {
            float s = rloc[fm][rg];
            s += __shfl_xor(s, 1);
            s += __shfl_xor(s, 2);
            s += __shfl_xor(s, 4);
            s += __shfl_xor(s, 8);
            if (l15 == 0)
                atomicAdd(&rs[p * NROW + ci * TILE + wrow * 64 + fm * 16 + qd * 4 + rg], s);
        }
#pragma unroll
    for (int fn = 0; fn < 4; fn++) {
        float s = cloc[fn];
        s += __shfl_xor(s, 16);
        s += __shfl_xor(s, 32);
        if (qd == 0)
            atomicAdd(&cs[p * NROW + cj * TILE + wcol * 64 + fn * 16 + l15], s);
    }
}

// ---- K10: final loss reduction ----
__global__ void k10_loss(const float* __restrict__ diag, const float* __restrict__ rs,
                         const float* __restrict__ cs, float* __restrict__ outp) {
    float acc = 0.f;
    for (int i = threadIdx.x; i < 3 * NROW; i += 256)
        acc += 2.f * diag[i] - logf(rs[i]) - logf(cs[i]);
    int lane = threadIdx.x & 63, wv = threadIdx.x >> 6;
    for (int o = 32; o; o >>= 1) acc += __shfl_down(acc, o);
    __shared__ float red[4];
    if (lane == 0) red[wv] = acc;
    __syncthreads();
    if (threadIdx.x == 0) {
        float tot = red[0] + red[1] + red[2] + red[3];
        outp[(size_t)NROW * 768] = -tot / (NROW * 6.0f);
    }
}

extern "C" void kernel_launch(void* const* d_in, const int* in_sizes, int n_in,
                              void* d_out, int out_size, void* d_ws, size_t ws_size,
                              hipStream_t stream) {
    const float* t   = (const float*)d_in[0];
    const float* a   = (const float*)d_in[1];
    const float* v   = (const float*)d_in[2];
    const float* Wfc = (const float*)d_in[3];
    const float* bfc = (const float*)d_in[4];
    const float* Wh  = (const float*)d_in[5];
    const float* bh  = (const float*)d_in[6];
    float* outp = (float*)d_out;
    float* ws = (float*)d_ws;

    // workspace layout (floats); all offsets 16B-aligned
    float* sq    = ws;                       // 12288
    float* d2    = sq + 12288;               // 2359296 (dead after k2 -> xnb)
    float* HbF   = d2 + 2359296;             // 1179648 (fp16 Hb 12288x192)
    float* HbTF  = HbF + 1179648;            // 1179648
    float* degE  = HbTF + 1179648;           // 12288
    float* degV  = degE + 12288;             // 12288
    float* featF = degV + 12288;             // 3145728 (fp16 featb 64x192x512)
    float* WfcTF = featF + 3145728;          // 65536   (fp16 256x512)
    float* WhTF  = WfcTF + 65536;            // 32768   (fp16 256x256)
    float* XTF   = WhTF + 32768;             // 1572864 (fp16 64x256x192)
    float* ETF   = XTF + 1572864;            // 1572864
    float* YF    = ETF + 1572864;            // 1572864 (fp16 12288x256)
    float* rs    = YF + 1572864;             // 12288
    float* cs    = rs + 12288;               // 12288
    float* diag  = cs + 12288;               // 12288

    _Float16* Hb    = (_Float16*)HbF;
    _Float16* HbT   = (_Float16*)HbTF;
    _Float16* featb = (_Float16*)featF;
    _Float16* WfcT  = (_Float16*)WfcTF;
    _Float16* WhT   = (_Float16*)WhTF;
    _Float16* XT    = (_Float16*)XTF;
    _Float16* ET    = (_Float16*)ETF;
    _Float16* Y     = (_Float16*)YF;
    ushort*   xnb   = (ushort*)d2;           // bf16[3][4096][256] (swizzled)

    kprep  <<<10608, 256, 0, stream>>>(t, a, v, Wfc, Wh, featb, WfcT, WhT,
                                       sq, rs, cs, degV, HbT);
    k1_d2  <<<dim3(6, 64), 256, 0, stream>>>(t, a, v, sq, d2);
    k2_topk<<<3072, 256, 0, stream>>>(d2, Hb, HbT, degE, degV);
    k3_x   <<<dim3(4, 64), 192, 0, stream>>>(WfcT, featb, bfc, XT);
    k4_E   <<<dim3(4, 64), 192, 0, stream>>>(XT, Hb, degE, ET);
    k5_Y   <<<dim3(3, 64), 256, 0, stream>>>(HbT, ET, degV, Y);
    k6_out <<<192, 256, 0, stream>>>(Y, WhT, bh, outp);
    k7_norm<<<3072, 256, 0, stream>>>(outp, xnb);
    k9_mfma<<<dim3(32, 32, 3), 256, 0, stream>>>(xnb, rs, cs, diag);
    k10_loss<<<1, 256, 0, stream>>>(diag, rs, cs, outp);
}

// Round 7
// 288.910 us; speedup vs baseline: 1.5715x; 1.0095x over previous
//
#include <hip/hip_runtime.h>
#include <math.h>

// Problem constants: D=64 dialogues, L=64, DIM=512, G=256
// m = 3*L = 192 nodes/hyperedges per dialogue, k = 12, N = D*L = 4096
#define NDIAL 64
#define M3    192
#define DIMF  512
#define GDIM  256
#define NROW  4096
#define TOPK  12
#define INV_TAU (1.0f/0.07f)

typedef __attribute__((ext_vector_type(8))) short bf16x8;
typedef __attribute__((ext_vector_type(4))) float f32x4;
typedef __attribute__((ext_vector_type(8))) ushort us8;
typedef _Float16 f16x8 __attribute__((ext_vector_type(8)));
typedef _Float16 f16x4v __attribute__((ext_vector_type(4)));
typedef __attribute__((address_space(3))) ushort lds_us;
typedef const __attribute__((address_space(1))) ushort gm_us;

__device__ __forceinline__ ushort f2bf(float f) {
    unsigned u = __float_as_uint(f);
    unsigned r = (u + 0x7fff + ((u >> 16) & 1)) >> 16;   // RNE
    return (ushort)r;
}

// ---------------------------------------------------------------------------
// fp32 64x64 tile GEMM helper (k1 only: top-k selection must stay fp32).
// ---------------------------------------------------------------------------
template<int KDIM>
__device__ __forceinline__ void mm64bt(
    const float* __restrict__ A, int lda,
    const float* __restrict__ B, int ldb,
    float acc[4][4])
{
    __shared__ float As[64][33];
    __shared__ float Bs[32][68];
    const int tid = threadIdx.x;
    const int tx = tid & 15, ty = tid >> 4;

#pragma unroll
    for (int r = 0; r < 4; r++)
#pragma unroll
        for (int c = 0; c < 4; c++) acc[r][c] = 0.f;

    for (int k0 = 0; k0 < KDIM; k0 += 32) {
#pragma unroll
        for (int i = 0; i < 2; i++) {
            int f = tid + i * 256;
            int m = f >> 3, k4 = f & 7;
            const float4 v4 = *(const float4*)(A + (size_t)m * lda + k0 + k4 * 4);
            As[m][k4 * 4 + 0] = v4.x;
            As[m][k4 * 4 + 1] = v4.y;
            As[m][k4 * 4 + 2] = v4.z;
            As[m][k4 * 4 + 3] = v4.w;
        }
#pragma unroll
        for (int i = 0; i < 2; i++) {
            int f = tid + i * 256;
            int n = f >> 3, k4 = f & 7;
            const float4 v4 = *(const float4*)(B + (size_t)n * ldb + k0 + k4 * 4);
            Bs[k4 * 4 + 0][n] = v4.x;
            Bs[k4 * 4 + 1][n] = v4.y;
            Bs[k4 * 4 + 2][n] = v4.z;
            Bs[k4 * 4 + 3][n] = v4.w;
        }
        __syncthreads();
#pragma unroll
        for (int kk = 0; kk < 32; kk++) {
            float4 b = *(const float4*)&Bs[kk][tx * 4];
#pragma unroll
            for (int r = 0; r < 4; r++) {
                float av = As[ty * 4 + r][kk];
                acc[r][0] += av * b.x;
                acc[r][1] += av * b.y;
                acc[r][2] += av * b.z;
                acc[r][3] += av * b.w;
            }
        }
        __syncthreads();
    }
}

// ---------------------------------------------------------------------------
// fp16 MFMA GEMM helper: block = 64 rows x (NW*64) cols, NW waves (wave w
// owns col block w). A: [M][K] row-major; B: "B^T layout" [N][K] row-major.
// C/D: row = fm*16 + qd*4 + rg, col = w*64 + fn*16 + l15.
// ---------------------------------------------------------------------------
template<int KD, int NW>
__device__ __forceinline__ void hgemm_bt(const _Float16* __restrict__ A, int lda,
                                         const _Float16* __restrict__ B, int ldb,
                                         f32x4 acc[4][4]) {
    __shared__ __align__(16) _Float16 As[64 * 40];
    __shared__ __align__(16) _Float16 Bs[NW * 64 * 40];
    const int tid = threadIdx.x;
    const int lane = tid & 63, w = tid >> 6;
    const int qd = lane >> 4, l15 = lane & 15;

#pragma unroll
    for (int fm = 0; fm < 4; fm++)
#pragma unroll
        for (int fn = 0; fn < 4; fn++)
            acc[fm][fn] = (f32x4){0.f, 0.f, 0.f, 0.f};

    for (int k0 = 0; k0 < KD; k0 += 32) {
        for (int f = tid; f < 256; f += NW * 64) {
            int row = f >> 2, c8 = f & 3;
            *(float4*)&As[row * 40 + c8 * 8] =
                *(const float4*)&A[(size_t)row * lda + k0 + c8 * 8];
        }
#pragma unroll
        for (int i = 0; i < 4; i++) {
            int f = tid + i * NW * 64;
            int row = f >> 2, c8 = f & 3;
            *(float4*)&Bs[row * 40 + c8 * 8] =
                *(const float4*)&B[(size_t)row * ldb + k0 + c8 * 8];
        }
        __syncthreads();
        f16x8 af[4], bfr[4];
#pragma unroll
        for (int fm = 0; fm < 4; fm++)
            af[fm] = *(const f16x8*)&As[(fm * 16 + l15) * 40 + qd * 8];
#pragma unroll
        for (int fn = 0; fn < 4; fn++)
            bfr[fn] = *(const f16x8*)&Bs[(w * 64 + fn * 16 + l15) * 40 + qd * 8];
#pragma unroll
        for (int fm = 0; fm < 4; fm++)
#pragma unroll
            for (int fn = 0; fn < 4; fn++)
                acc[fm][fn] = __builtin_amdgcn_mfma_f32_16x16x32_f16(
                    af[fm], bfr[fn], acc[fm][fn], 0, 0, 0);
        __syncthreads();
    }
}

__device__ __forceinline__ const float* node_ptr(const float* t, const float* a,
                                                 const float* v, int d, int j) {
    int mod = j >> 6, i = j & 63;
    const float* base = (mod == 0) ? t : (mod == 1) ? a : v;
    return base + (size_t)(d * 64 + i) * DIMF;
}

// ---- KPREP: fused fp16 conversions + per-node norms + zero-init ----
__global__ void kprep(const float* __restrict__ t, const float* __restrict__ a,
                      const float* __restrict__ v, const float* __restrict__ Wfc,
                      const float* __restrict__ Wh, _Float16* __restrict__ featb,
                      _Float16* __restrict__ WfcT, _Float16* __restrict__ WhT,
                      float* __restrict__ sq, float* __restrict__ rs,
                      float* __restrict__ cs, float* __restrict__ degV,
                      _Float16* __restrict__ HbT) {
    int b = blockIdx.x, tid = threadIdx.x;
    if (b < 6144) {
        int e = (b * 256 + tid) * 4;
        int d = e / (M3 * DIMF);
        int rem = e % (M3 * DIMF);
        int n = rem / DIMF, kk = rem % DIMF;
        int mod = n >> 6, i = n & 63;
        const float* src = ((mod == 0) ? t : (mod == 1) ? a : v)
                           + (size_t)(d * 64 + i) * DIMF + kk;
        float4 x = *(const float4*)src;
        f16x4v o = {(_Float16)x.x, (_Float16)x.y, (_Float16)x.z, (_Float16)x.w};
        *(f16x4v*)&featb[e] = o;
    } else if (b < 6272) {
        int e = ((b - 6144) * 256 + tid) * 4;
        int g = e >> 9, kk = e & 511;
        f16x4v o = {(_Float16)Wfc[(size_t)(kk + 0) * GDIM + g],
                    (_Float16)Wfc[(size_t)(kk + 1) * GDIM + g],
                    (_Float16)Wfc[(size_t)(kk + 2) * GDIM + g],
                    (_Float16)Wfc[(size_t)(kk + 3) * GDIM + g]};
        *(f16x4v*)&WfcT[(size_t)g * DIMF + kk] = o;
    } else if (b < 6336) {
        int e = ((b - 6272) * 256 + tid) * 4;
        int go = e >> 8, g = e & 255;
        f16x4v o = {(_Float16)Wh[(size_t)(g + 0) * GDIM + go],
                    (_Float16)Wh[(size_t)(g + 1) * GDIM + go],
                    (_Float16)Wh[(size_t)(g + 2) * GDIM + go],
                    (_Float16)Wh[(size_t)(g + 3) * GDIM + go]};
        *(f16x4v*)&WhT[(size_t)go * GDIM + g] = o;
    } else if (b < 9408) {
        int lane = tid & 63, wv = tid >> 6;
        int n = (b - 6336) * 4 + wv;
        int d = n / M3, j = n % M3;
        const float4* s4 = (const float4*)node_ptr(t, a, v, d, j);
        float s = 0.f;
#pragma unroll
        for (int q = 0; q < 2; q++) {
            float4 x = s4[lane + q * 64];
            s += x.x * x.x + x.y * x.y + x.z * x.z + x.w * x.w;
        }
        for (int o = 32; o; o >>= 1) s += __shfl_down(s, o);
        if (lane == 0) sq[n] = s;
    } else if (b < 9456) {
        int i = (b - 9408) * 256 + tid;
        rs[i] = 0.f; cs[i] = 0.f; degV[i] = 0.f;
    } else {
        int i = (b - 9456) * 256 + tid;
        ulonglong2 z = {0ull, 0ull};
        *(ulonglong2*)&HbT[(size_t)i * 8] = z;
    }
}

// ---- K1: clamped squared distances; symmetric -> 6 of 9 tiles ----
__global__ void k1_d2(const float* __restrict__ t, const float* __restrict__ a,
                      const float* __restrict__ v, const float* __restrict__ sq,
                      float* __restrict__ d2) {
    int tileid = blockIdx.x;             // 0..5 upper triangle
    int d = blockIdx.y;
    int bi = (tileid < 3) ? 0 : (tileid < 5) ? 1 : 2;
    int bj = (tileid < 3) ? tileid : (tileid < 5) ? tileid - 2 : 2;
    const float* A = ((bi == 0) ? t : (bi == 1) ? a : v) + (size_t)d * 64 * DIMF;
    const float* B = ((bj == 0) ? t : (bj == 1) ? a : v) + (size_t)d * 64 * DIMF;
    float acc[4][4];
    mm64bt<DIMF>(A, DIMF, B, DIMF, acc);
    int tx = threadIdx.x & 15, ty = threadIdx.x >> 4;
    const float* sqd = sq + d * M3;
    float* outp = d2 + (size_t)d * M3 * M3;
#pragma unroll
    for (int r = 0; r < 4; r++)
#pragma unroll
        for (int c = 0; c < 4; c++) {
            int il = bi * 64 + ty * 4 + r;
            int jl = bj * 64 + tx * 4 + c;
            float vv = fmaxf(sqd[il] + sqd[jl] - 2.f * acc[r][c], 0.f);
            outp[(size_t)il * M3 + jl] = vv;
            if (bi != bj) outp[(size_t)jl * M3 + il] = vv;
        }
}

// ---- K2: wave-per-row top-12 + fp16 H build + HbT scatter + degrees ----
__global__ void k2_topk(const float* __restrict__ d2, _Float16* __restrict__ Hb,
                        _Float16* __restrict__ HbT, float* __restrict__ degE,
                        float* __restrict__ degV) {
    int lane = threadIdx.x & 63, wv = threadIdx.x >> 6;
    int r = blockIdx.x * 4 + wv;                 // 0..12287
    int d = r / M3, e = r % M3;
    const float* row = d2 + (size_t)r * M3;
    float w0 = row[lane], w1 = row[lane + 64], w2 = row[lane + 128];
    bool s0 = false, s1 = false, s2 = false;
#pragma unroll
    for (int it = 0; it < TOPK; it++) {
        float bv = w0; int bi = lane;
        if (w1 < bv) { bv = w1; bi = lane + 64; }
        if (w2 < bv) { bv = w2; bi = lane + 128; }
#pragma unroll
        for (int o = 1; o < 64; o <<= 1) {
            float ov = __shfl_xor(bv, o);
            int   oi = __shfl_xor(bi, o);
            if (ov < bv || (ov == bv && oi < bi)) { bv = ov; bi = oi; }
        }
        if (bi == lane)            { s0 = true; w0 = 3.4e38f; }
        else if (bi == lane + 64)  { s1 = true; w1 = 3.4e38f; }
        else if (bi == lane + 128) { s2 = true; w2 = 3.4e38f; }
    }
    int u = e / 3;
    if (lane == u) { s0 = true; s1 = true; s2 = true; }
    float f0 = s0 ? 1.f : 0.f, f1 = s1 ? 1.f : 0.f, f2 = s2 ? 1.f : 0.f;
    _Float16* Hrow = Hb + (size_t)r * M3;
    Hrow[lane] = (_Float16)f0;
    Hrow[lane + 64] = (_Float16)f1;
    Hrow[lane + 128] = (_Float16)f2;
    float cnt = f0 + f1 + f2;
#pragma unroll
    for (int o = 1; o < 64; o <<= 1) cnt += __shfl_xor(cnt, o);
    if (lane == 0) degE[r] = cnt;
    float* dv = degV + d * M3;
    _Float16* HT = HbT + (size_t)d * M3 * M3;
    if (s0) { atomicAdd(&dv[lane], 1.f);       HT[(size_t)lane * M3 + e] = (_Float16)1.f; }
    if (s1) { atomicAdd(&dv[lane + 64], 1.f);  HT[(size_t)(lane + 64) * M3 + e] = (_Float16)1.f; }
    if (s2) { atomicAdd(&dv[lane + 128], 1.f); HT[(size_t)(lane + 128) * M3 + e] = (_Float16)1.f; }
}

// ---- K3': XT = (feat @ Wfc)^T + bfc, per dialogue. XT[d][g][n] fp16 ----
__global__ void k3_x(const _Float16* __restrict__ WfcT, const _Float16* __restrict__ featb,
                     const float* __restrict__ bfc, _Float16* __restrict__ XT) {
    int gb = blockIdx.x, d = blockIdx.y;
    const _Float16* A = WfcT + (size_t)gb * 64 * DIMF;
    const _Float16* B = featb + (size_t)d * M3 * DIMF;
    f32x4 acc[4][4];
    hgemm_bt<DIMF, 3>(A, DIMF, B, DIMF, acc);
    int lane = threadIdx.x & 63, w = threadIdx.x >> 6;
    int qd = lane >> 4, l15 = lane & 15;
    _Float16* out = XT + (size_t)d * GDIM * M3;
#pragma unroll
    for (int fm = 0; fm < 4; fm++)
#pragma unroll
        for (int rg = 0; rg < 4; rg++) {
            int g = gb * 64 + fm * 16 + qd * 4 + rg;
            float bias = bfc[g];
#pragma unroll
            for (int fn = 0; fn < 4; fn++) {
                int n = w * 64 + fn * 16 + l15;
                out[(size_t)g * M3 + n] = (_Float16)(acc[fm][fn][rg] + bias);
            }
        }
}

// ---- K4': ET = (H @ X)^T / deg_e = XT @ H(B^T).  ET[d][g][e] fp16 ----
__global__ void k4_E(const _Float16* __restrict__ XT, const _Float16* __restrict__ Hb,
                     const float* __restrict__ degE, _Float16* __restrict__ ET) {
    int gb = blockIdx.x, d = blockIdx.y;
    const _Float16* A = XT + (size_t)d * GDIM * M3 + (size_t)gb * 64 * M3;
    const _Float16* B = Hb + (size_t)d * M3 * M3;
    f32x4 acc[4][4];
    hgemm_bt<M3, 3>(A, M3, B, M3, acc);
    int lane = threadIdx.x & 63, w = threadIdx.x >> 6;
    int qd = lane >> 4, l15 = lane & 15;
    float ide[4];
#pragma unroll
    for (int fn = 0; fn < 4; fn++)
        ide[fn] = 1.f / degE[d * M3 + w * 64 + fn * 16 + l15];
    _Float16* out = ET + (size_t)d * GDIM * M3;
#pragma unroll
    for (int fm = 0; fm < 4; fm++)
#pragma unroll
        for (int rg = 0; rg < 4; rg++) {
            int g = gb * 64 + fm * 16 + qd * 4 + rg;
#pragma unroll
            for (int fn = 0; fn < 4; fn++) {
                int e = w * 64 + fn * 16 + l15;
                out[(size_t)g * M3 + e] = (_Float16)(acc[fm][fn][rg] * ide[fn]);
            }
        }
}

// ---- K5: Y = (H^T @ E) / deg_v = HbT @ ET(B^T).  Y[d][n][g] fp16 ----
__global__ void k5_Y(const _Float16* __restrict__ HbT, const _Float16* __restrict__ ET,
                     const float* __restrict__ degV, _Float16* __restrict__ Y) {
    int nb = blockIdx.x, d = blockIdx.y;
    const _Float16* A = HbT + (size_t)d * M3 * M3 + (size_t)nb * 64 * M3;
    const _Float16* B = ET + (size_t)d * GDIM * M3;
    f32x4 acc[4][4];
    hgemm_bt<M3, 4>(A, M3, B, M3, acc);
    int lane = threadIdx.x & 63, w = threadIdx.x >> 6;
    int qd = lane >> 4, l15 = lane & 15;
    _Float16* out = Y + ((size_t)d * M3 + nb * 64) * GDIM;
#pragma unroll
    for (int fm = 0; fm < 4; fm++)
#pragma unroll
        for (int rg = 0; rg < 4; rg++) {
            int ml = fm * 16 + qd * 4 + rg;
            float idv = 1.f / degV[d * M3 + nb * 64 + ml];
#pragma unroll
            for (int fn = 0; fn < 4; fn++) {
                int g = w * 64 + fn * 16 + l15;
                out[(size_t)ml * GDIM + g] = (_Float16)(acc[fm][fn][rg] * idv);
            }
        }
}

// ---- K6: out = relu(Y @ Wh + bh) -> fp32 d_out; FUSED row-normalize ->
//      bf16 xnb (swizzled). Replaces old k6 + k7. ----
__global__ __launch_bounds__(256) void k6_out(const _Float16* __restrict__ Y,
                                              const _Float16* __restrict__ WhT,
                                              const float* __restrict__ bh,
                                              float* __restrict__ outp,
                                              ushort* __restrict__ xnb) {
    __shared__ float tile[64 * 256];
    __shared__ float ssq[64];
    int b = blockIdx.x, tid = threadIdx.x;
    if (tid < 64) ssq[tid] = 0.f;                // ordered by hgemm's first sync
    const _Float16* A = Y + (size_t)b * 64 * GDIM;
    f32x4 acc[4][4];
    hgemm_bt<GDIM, 4>(A, GDIM, WhT, GDIM, acc);
    int lane = tid & 63, w = tid >> 6;
    int qd = lane >> 4, l15 = lane & 15;
    int d = b / 3, mod = b % 3;
    float bb[4];
#pragma unroll
    for (int fn = 0; fn < 4; fn++)
        bb[fn] = bh[w * 64 + fn * 16 + l15];
#pragma unroll
    for (int fm = 0; fm < 4; fm++)
#pragma unroll
        for (int rg = 0; rg < 4; rg++) {
            int i = fm * 16 + qd * 4 + rg;       // row within 64-row band
            float* orow = outp + (size_t)(d * 64 + i) * 768 + mod * GDIM;
            float s2 = 0.f;
#pragma unroll
            for (int fn = 0; fn < 4; fn++) {
                int go = w * 64 + fn * 16 + l15;
                float vv = fmaxf(acc[fm][fn][rg] + bb[fn], 0.f);
                orow[go] = vv;
                tile[i * 256 + go] = vv;
                s2 += vv * vv;
            }
            s2 += __shfl_xor(s2, 1);
            s2 += __shfl_xor(s2, 2);
            s2 += __shfl_xor(s2, 4);
            s2 += __shfl_xor(s2, 8);
            if (l15 == 0) atomicAdd(&ssq[i], s2);
        }
    __syncthreads();
    if (tid < 64) ssq[tid] = 1.f / (sqrtf(ssq[tid]) + 1e-8f);
    __syncthreads();
    // emit bf16 normalized rows, chunk-swizzled for k9's DMA staging:
    // chunk c of row r stored at slot (c&24)|((c&7)^(r&7))
#pragma unroll
    for (int it = 0; it < 8; it++) {
        int f = tid + it * 256;                  // 0..2047 chunk ids
        int row = f >> 5, c = f & 31;
        float4 xa = *(const float4*)&tile[row * 256 + c * 8];
        float4 xb = *(const float4*)&tile[row * 256 + c * 8 + 4];
        float iv = ssq[row];
        us8 o = {f2bf(xa.x * iv), f2bf(xa.y * iv), f2bf(xa.z * iv), f2bf(xa.w * iv),
                 f2bf(xb.x * iv), f2bf(xb.y * iv), f2bf(xb.z * iv), f2bf(xb.w * iv)};
        int rx = d * 64 + row;                   // rx&7 == row&7 (d*64 % 8 == 0)
        int slot = (c & 24) | ((c & 7) ^ (row & 7));
        *(us8*)&xnb[((size_t)mod * NROW + rx) * GDIM + slot * 8] = o;
    }
}

// ---- K9: bf16 MFMA sim, 256x256 tiles, 8 waves, global_load_lds staging.
//      NO device fences (R5 lesson: they evict shared L2 -> 3x slowdown). ----
#define TILE2 256
__global__ __launch_bounds__(512, 2) void k9_mfma(const ushort* __restrict__ xnb,
                                                  float* __restrict__ rs,
                                                  float* __restrict__ cs,
                                                  float* __restrict__ diag) {
    int cj = blockIdx.x, ci = blockIdx.y, p = blockIdx.z;
    int px = (p == 2) ? 1 : 0;
    int py = (p == 0) ? 1 : 2;
    const ushort* A = xnb + ((size_t)px * NROW + ci * TILE2) * GDIM;
    const ushort* B = xnb + ((size_t)py * NROW + cj * TILE2) * GDIM;

    __shared__ __align__(16) ushort As[TILE2 * 64];
    __shared__ __align__(16) ushort Bs[TILE2 * 64];

    const int tid = threadIdx.x;
    const int lane = tid & 63, w = tid >> 6;     // 8 waves
    const int wrow = w >> 2, wcol = w & 3;       // 2 x 4 wave grid
    const int qd = lane >> 4, l15 = lane & 15;
    const int lrow = lane >> 3, lslot = lane & 7;

    f32x4 acc[8][4] = {};

    for (int kh = 0; kh < 4; kh++) {             // BK = 64 per stage
#pragma unroll
        for (int j = 0; j < 4; j++) {
            int rr = w * 32 + j * 8 + lrow;      // per-lane global row
            __builtin_amdgcn_global_load_lds(
                (gm_us*)(A + (size_t)rr * GDIM + kh * 64 + lslot * 8),
                (lds_us*)&As[(w * 32 + j * 8) * 64], 16, 0, 0);
            __builtin_amdgcn_global_load_lds(
                (gm_us*)(B + (size_t)rr * GDIM + kh * 64 + lslot * 8),
                (lds_us*)&Bs[(w * 32 + j * 8) * 64], 16, 0, 0);
        }
        __syncthreads();
#pragma unroll
        for (int kk = 0; kk < 2; kk++) {
            bf16x8 af[8], bfv[4];
#pragma unroll
            for (int fm = 0; fm < 8; fm++) {
                int ar = wrow * 128 + fm * 16 + l15;
                af[fm] = *(const bf16x8*)&As[ar * 64 + ((kk * 4 + qd) ^ (ar & 7)) * 8];
            }
#pragma unroll
            for (int fn = 0; fn < 4; fn++) {
                int br = wcol * 64 + fn * 16 + l15;
                bfv[fn] = *(const bf16x8*)&Bs[br * 64 + ((kk * 4 + qd) ^ (br & 7)) * 8];
            }
#pragma unroll
            for (int fm = 0; fm < 8; fm++)
#pragma unroll
                for (int fn = 0; fn < 4; fn++)
                    acc[fm][fn] = __builtin_amdgcn_mfma_f32_16x16x32_bf16(
                        af[fm], bfv[fn], acc[fm][fn], 0, 0, 0);
        }
        __syncthreads();
    }

    // epilogue: exp, row/col partial sums, diagonal capture
    float rloc[8][4] = {};
    float cloc[4] = {};
#pragma unroll
    for (int fm = 0; fm < 8; fm++)
#pragma unroll
        for (int fn = 0; fn < 4; fn++)
#pragma unroll
            for (int rg = 0; rg < 4; rg++) {
                float s = acc[fm][fn][rg] * INV_TAU;
                float e = __expf(s);
                rloc[fm][rg] += e;
                cloc[fn] += e;
                int grow = ci * TILE2 + wrow * 128 + fm * 16 + qd * 4 + rg;
                int gcol = cj * TILE2 + wcol * 64 + fn * 16 + l15;
                if (grow == gcol) diag[p * NROW + grow] = s;
            }
#pragma unroll
    for (int fm = 0; fm < 8; fm++)
#pragma unroll
        for (int rg = 0; rg < 4; rg++) {
            float s = rloc[fm][rg];
            s += __shfl_xor(s, 1);
            s += __shfl_xor(s, 2);
            s += __shfl_xor(s, 4);
            s += __shfl_xor(s, 8);
            if (l15 == 0)
                atomicAdd(&rs[p * NROW + ci * TILE2 + wrow * 128 + fm * 16 + qd * 4 + rg], s);
        }
#pragma unroll
    for (int fn = 0; fn < 4; fn++) {
        float s = cloc[fn];
        s += __shfl_xor(s, 16);
        s += __shfl_xor(s, 32);
        if (qd == 0)
            atomicAdd(&cs[p * NROW + cj * TILE2 + wcol * 64 + fn * 16 + l15], s);
    }
}

// ---- K10: final loss reduction ----
__global__ void k10_loss(const float* __restrict__ diag, const float* __restrict__ rs,
                         const float* __restrict__ cs, float* __restrict__ outp) {
    float acc = 0.f;
    for (int i = threadIdx.x; i < 3 * NROW; i += 256)
        acc += 2.f * diag[i] - logf(rs[i]) - logf(cs[i]);
    int lane = threadIdx.x & 63, wv = threadIdx.x >> 6;
    for (int o = 32; o; o >>= 1) acc += __shfl_down(acc, o);
    __shared__ float red[4];
    if (lane == 0) red[wv] = acc;
    __syncthreads();
    if (threadIdx.x == 0) {
        float tot = red[0] + red[1] + red[2] + red[3];
        outp[(size_t)NROW * 768] = -tot / (NROW * 6.0f);
    }
}

extern "C" void kernel_launch(void* const* d_in, const int* in_sizes, int n_in,
                              void* d_out, int out_size, void* d_ws, size_t ws_size,
                              hipStream_t stream) {
    const float* t   = (const float*)d_in[0];
    const float* a   = (const float*)d_in[1];
    const float* v   = (const float*)d_in[2];
    const float* Wfc = (const float*)d_in[3];
    const float* bfc = (const float*)d_in[4];
    const float* Wh  = (const float*)d_in[5];
    const float* bh  = (const float*)d_in[6];
    float* outp = (float*)d_out;
    float* ws = (float*)d_ws;

    // workspace layout (floats); all offsets 16B-aligned
    float* sq    = ws;                       // 12288
    float* d2    = sq + 12288;               // 2359296 (dead after k2 -> xnb)
    float* HbF   = d2 + 2359296;             // 1179648 (fp16 Hb 12288x192)
    float* HbTF  = HbF + 1179648;            // 1179648
    float* degE  = HbTF + 1179648;           // 12288
    float* degV  = degE + 12288;             // 12288
    float* featF = degV + 12288;             // 3145728 (fp16 featb 64x192x512)
    float* WfcTF = featF + 3145728;          // 65536   (fp16 256x512)
    float* WhTF  = WfcTF + 65536;            // 32768   (fp16 256x256)
    float* XTF   = WhTF + 32768;             // 1572864 (fp16 64x256x192)
    float* ETF   = XTF + 1572864;            // 1572864
    float* YF    = ETF + 1572864;            // 1572864 (fp16 12288x256)
    float* rs    = YF + 1572864;             // 12288
    float* cs    = rs + 12288;               // 12288
    float* diag  = cs + 12288;               // 12288

    _Float16* Hb    = (_Float16*)HbF;
    _Float16* HbT   = (_Float16*)HbTF;
    _Float16* featb = (_Float16*)featF;
    _Float16* WfcT  = (_Float16*)WfcTF;
    _Float16* WhT   = (_Float16*)WhTF;
    _Float16* XT    = (_Float16*)XTF;
    _Float16* ET    = (_Float16*)ETF;
    _Float16* Y     = (_Float16*)YF;
    ushort*   xnb   = (ushort*)d2;           // bf16[3][4096][256] (swizzled)

    kprep  <<<10608, 256, 0, stream>>>(t, a, v, Wfc, Wh, featb, WfcT, WhT,
                                       sq, rs, cs, degV, HbT);
    k1_d2  <<<dim3(6, 64), 256, 0, stream>>>(t, a, v, sq, d2);
    k2_topk<<<3072, 256, 0, stream>>>(d2, Hb, HbT, degE, degV);
    k3_x   <<<dim3(4, 64), 192, 0, stream>>>(WfcT, featb, bfc, XT);
    k4_E   <<<dim3(4, 64), 192, 0, stream>>>(XT, Hb, degE, ET);
    k5_Y   <<<dim3(3, 64), 256, 0, stream>>>(HbT, ET, degV, Y);
    k6_out <<<192, 256, 0, stream>>>(Y, WhT, bh, outp, xnb);
    k9_mfma<<<dim3(16, 16, 3), 512, 0, stream>>>(xnb, rs, cs, diag);
    k10_loss<<<1, 256, 0, stream>>>(diag, rs, cs, outp);
}